// Round 5
// baseline (2546.302 us; speedup 1.0000x reference)
//
#include <hip/hip_runtime.h>
#include <cstddef>

#define EPS 1e-5f
#define NNODE 30000
#define NEDGE 360000
#define NFEAT 92
#define EF 41
#define D 64
#define LAY 3
#define FCW 128
#define NG 64

typedef unsigned short bf16;

__device__ __forceinline__ float b2f(bf16 u) { return __uint_as_float(((unsigned)u) << 16); }
__device__ __forceinline__ float lo2f(unsigned u) { return __uint_as_float(u << 16); }
__device__ __forceinline__ float hi2f(unsigned u) { return __uint_as_float(u & 0xffff0000u); }
__device__ __forceinline__ bf16 f2b(float f) {
    unsigned u = __float_as_uint(f);
    unsigned r = (u + 0x7FFFu + ((u >> 16) & 1u)) >> 16;
    return (bf16)r;
}
__device__ __forceinline__ float softplusf(float x) {
    return fmaxf(x, 0.0f) + log1pf(expf(-fabsf(x)));
}

// ---------------- embedding matmul: pre = X[N,92] @ W[92,64] + b, accumulate col stats
#define EMB_RPB 64
__global__ __launch_bounds__(256) void k_emb_mm(const float* __restrict__ X, const float* __restrict__ W,
                                                const float* __restrict__ bias, float* __restrict__ pre,
                                                float* __restrict__ stats, int N) {
    __shared__ float xs[EMB_RPB][NFEAT];
    __shared__ float red[4][2][64];
    int tid = threadIdx.x;
    int lane = tid & 63, wid = tid >> 6;
    int r0 = blockIdx.x * EMB_RPB;
    float w[NFEAT];
#pragma unroll
    for (int k = 0; k < NFEAT; k++) w[k] = W[k * D + lane];
    float bcol = bias[lane];
    for (int i = tid; i < EMB_RPB * (NFEAT / 4); i += 256) {
        int rr = i / (NFEAT / 4), kk = i - rr * (NFEAT / 4);
        int r = r0 + rr;
        float4 v = (r < N) ? ((const float4*)(X + (size_t)r * NFEAT))[kk] : make_float4(0, 0, 0, 0);
        *(float4*)&xs[rr][kk * 4] = v;
    }
    __syncthreads();
    float s0 = 0.f, s1 = 0.f;
    for (int rr = wid * 16; rr < wid * 16 + 16; rr++) {
        int r = r0 + rr;
        if (r >= N) break;
        float acc = bcol;
#pragma unroll
        for (int k4 = 0; k4 < NFEAT; k4 += 4) {
            float4 xv = *(const float4*)&xs[rr][k4];
            acc += xv.x * w[k4] + xv.y * w[k4 + 1] + xv.z * w[k4 + 2] + xv.w * w[k4 + 3];
        }
        pre[r * D + lane] = acc;
        s0 += acc; s1 += acc * acc;
    }
    red[wid][0][lane] = s0; red[wid][1][lane] = s1;
    __syncthreads();
    if (tid < 64) {
        float a = red[0][0][lane] + red[1][0][lane] + red[2][0][lane] + red[3][0][lane];
        float b = red[0][1][lane] + red[1][1][lane] + red[2][1][lane] + red[3][1][lane];
        atomicAdd(&stats[lane], a);
        atomicAdd(&stats[64 + lane], b);
    }
}

// ---------------- BN + SiLU elementwise
__global__ void k_bnsilu(const float* __restrict__ pre, const float* __restrict__ stats,
                         const float* __restrict__ g, const float* __restrict__ beta,
                         float* __restrict__ h, int N, float invn) {
    int idx = blockIdx.x * blockDim.x + threadIdx.x;
    int total = N * D / 4;
    if (idx >= total) return;
    int c0 = (idx * 4) & 63;
    float4 p = ((const float4*)pre)[idx];
    float pv[4] = {p.x, p.y, p.z, p.w}, o[4];
#pragma unroll
    for (int t = 0; t < 4; t++) {
        int c = c0 + t;
        float m = stats[c] * invn;
        float v = stats[64 + c] * invn - m * m;
        float sc = g[c] * rsqrtf(fmaxf(v, 0.f) + EPS);
        float sh = beta[c] - m * sc;
        float y = sc * pv[t] + sh;
        o[t] = y / (1.f + expf(-y));
    }
    ((float4*)h)[idx] = make_float4(o[0], o[1], o[2], o[3]);
}

// ---------------- CSR build: histogram, block scan, fill
__global__ __launch_bounds__(256) void k_hist(const int* __restrict__ dst, int* __restrict__ deg, int E) {
    int i = blockIdx.x * 256 + threadIdx.x, gs = gridDim.x * 256;
    for (; i < E; i += gs) atomicAdd(&deg[dst[i]], 1);
}
__global__ __launch_bounds__(1024) void k_scan(const int* __restrict__ deg, int* __restrict__ rowptr,
                                               int* __restrict__ cursor, int N) {
    __shared__ int part[1024];
    int t = threadIdx.x;
    int chunk = (N + 1023) / 1024;
    int c0 = t * chunk, c1 = min(N, c0 + chunk);
    int s = 0;
    for (int i = c0; i < c1; i++) s += deg[i];
    part[t] = s;
    __syncthreads();
    for (int off = 1; off < 1024; off <<= 1) {
        int v = (t >= off) ? part[t - off] : 0;
        __syncthreads();
        part[t] += v;
        __syncthreads();
    }
    int base = (t == 0) ? 0 : part[t - 1];
    int r = base;
    for (int i = c0; i < c1; i++) {
        rowptr[i] = r; cursor[i] = r; r += deg[i];
    }
    if (t == 1023) rowptr[N] = part[1023];
}
__global__ __launch_bounds__(256) void k_fill(const int* __restrict__ dst, int* __restrict__ cursor,
                                              int* __restrict__ csr, int E) {
    int i = blockIdx.x * 256 + threadIdx.x, gs = gridDim.x * 256;
    for (; i < E; i += gs) {
        int p = atomicAdd(&cursor[dst[i]], 1);
        csr[p] = i;
    }
}

// ---------------- node projections -> ushort2 tables: SRCT[n*64+j]={gate,scr}, DSTT likewise
#define NP_RPB 64
__global__ __launch_bounds__(256) void k_nodeproj(const float* __restrict__ h, const float* __restrict__ Wc,
                                                  unsigned* __restrict__ SRC, unsigned* __restrict__ DST, int N) {
    __shared__ float hs[NP_RPB][D];   // 16 KB
    int tid = threadIdx.x;
    int j = tid & 63;
    int wid = __builtin_amdgcn_readfirstlane(tid >> 6);
    int pairIdx = wid & 1;            // 0: SRC (comb rows 0..63), 1: DST (rows 64..127)
    int half = wid >> 1;              // row-halves of the tile
    int roff = pairIdx * 64;
    float wg[D], wsx[D];
#pragma unroll
    for (int k = 0; k < D; k++) {
        wg[k] = Wc[(size_t)(roff + k) * 64 + j];
        wsx[k] = Wc[(size_t)(169 + roff + k) * 64 + j];
    }
    int r0 = blockIdx.x * NP_RPB;
    for (int i = tid; i < NP_RPB * D / 4; i += 256) {
        int rr = i >> 4, kk = (i & 15);
        int r = r0 + rr;
        float4 v = (r < N) ? ((const float4*)(h + (size_t)r * D))[kk] : make_float4(0, 0, 0, 0);
        *(float4*)&hs[rr][kk * 4] = v;
    }
    __syncthreads();
    unsigned* out = pairIdx ? DST : SRC;
    int rlo = half * 32, rhi = min(half * 32 + 32, N - r0);
    for (int rr = rlo; rr < rhi; rr++) {
        float ag = 0.f, as = 0.f;
#pragma unroll
        for (int k4 = 0; k4 < D; k4 += 4) {
            float4 xv = *(const float4*)&hs[rr][k4];
            ag += xv.x * wg[k4] + xv.y * wg[k4 + 1] + xv.z * wg[k4 + 2] + xv.w * wg[k4 + 3];
            as += xv.x * wsx[k4] + xv.y * wsx[k4 + 1] + xv.z * wsx[k4 + 2] + xv.w * wsx[k4 + 3];
        }
        unsigned pk = (unsigned)f2b(ag) | ((unsigned)f2b(as) << 16);
        out[(size_t)(r0 + rr) * 64 + j] = pk;
    }
}

// ---------------- conv GEMM: 64-edge tile; EW = ef@Wedge; + SRC/DST gathers -> pg/ps;
// stats on f32; store PREc[e*64+lane] = ushort2{pg,ps}; fused upd zeroing.
__global__ __launch_bounds__(256) void k_conv_gemm(const int* __restrict__ src, const int* __restrict__ dst,
                                                   const float* __restrict__ ef, const float* __restrict__ Wc,
                                                   const unsigned* __restrict__ SRCT, const unsigned* __restrict__ DSTT,
                                                   unsigned* __restrict__ PREc, float* __restrict__ stats,
                                                   float* __restrict__ upd, int E, int N) {
    __shared__ float els[64][44];      // 11.3 KB, row stride 176B (16B-aligned)
    __shared__ float red[4][4][64];
    int tid = threadIdx.x, lane = tid & 63;
    int wid = __builtin_amdgcn_readfirstlane(tid >> 6);
    {   // fused zeroing of upd
        int gsz = gridDim.x * 256;
        for (int i = blockIdx.x * 256 + tid; i < N * D; i += gsz) upd[i] = 0.f;
    }
    float wg[EF], wsc[EF];
#pragma unroll
    for (int k = 0; k < EF; k++) {
        wg[k] = Wc[(size_t)(128 + k) * 64 + lane];
        wsc[k] = Wc[(size_t)(169 + 128 + k) * 64 + lane];
    }
    int e0 = blockIdx.x * 64;
    const float* gbase = ef + (size_t)e0 * EF;
    for (int i = tid; i < 64 * EF; i += 256) {
        int rr = i / EF, kk = i - rr * EF;
        els[rr][kk] = gbase[i];
    }
    __syncthreads();
    float a0 = 0, a1 = 0, a2 = 0, a3 = 0;
#pragma unroll 1
    for (int jj = 0; jj < 16; jj++) {
        int le = wid * 16 + jj;
        int e = e0 + le;
        int sN = src[e], dN = dst[e];
        unsigned us = SRCT[(size_t)sN * 64 + lane];
        unsigned ud = DSTT[(size_t)dN * 64 + lane];
        float pg = lo2f(us) + lo2f(ud);
        float ps = hi2f(us) + hi2f(ud);
        float qg = 0.f, qs = 0.f;
#pragma unroll
        for (int k4 = 0; k4 < 40; k4 += 4) {
            float4 ev = *(const float4*)&els[le][k4];
            if (((k4 >> 2) & 1) == 0) {
                pg += ev.x * wg[k4] + ev.y * wg[k4 + 1] + ev.z * wg[k4 + 2] + ev.w * wg[k4 + 3];
                ps += ev.x * wsc[k4] + ev.y * wsc[k4 + 1] + ev.z * wsc[k4 + 2] + ev.w * wsc[k4 + 3];
            } else {
                qg += ev.x * wg[k4] + ev.y * wg[k4 + 1] + ev.z * wg[k4 + 2] + ev.w * wg[k4 + 3];
                qs += ev.x * wsc[k4] + ev.y * wsc[k4 + 1] + ev.z * wsc[k4 + 2] + ev.w * wsc[k4 + 3];
            }
        }
        {
            float ev = els[le][40];
            qg += ev * wg[40]; qs += ev * wsc[40];
        }
        pg += qg; ps += qs;
        a0 += pg; a1 += pg * pg; a2 += ps; a3 += ps * ps;
        unsigned pk = (unsigned)f2b(pg) | ((unsigned)f2b(ps) << 16);
        PREc[(size_t)e * 64 + lane] = pk;
    }
    red[wid][0][lane] = a0; red[wid][1][lane] = a1; red[wid][2][lane] = a2; red[wid][3][lane] = a3;
    __syncthreads();
    if (tid < 64) {
#pragma unroll
        for (int t = 0; t < 4; t++) {
            float v = red[0][t][lane] + red[1][t][lane] + red[2][t][lane] + red[3][t][lane];
            atomicAdd(&stats[t * 64 + lane], v);
        }
    }
}

// ---------------- conv apply: CSR over dst -> no atomics on upd; fused colstats of upd
__global__ __launch_bounds__(256) void k_conv_apply(const int* __restrict__ rowptr, const int* __restrict__ csr,
                                                    const unsigned* __restrict__ PREc, const float* __restrict__ stats,
                                                    const float* __restrict__ gg, const float* __restrict__ gb,
                                                    const float* __restrict__ sg, const float* __restrict__ sb,
                                                    float* __restrict__ upd, float* __restrict__ ustats,
                                                    int E, int N) {
    __shared__ float red[4][2][64];
    int tid = threadIdx.x, lane = tid & 63;
    int wid = __builtin_amdgcn_readfirstlane(tid >> 6);
    float invE = 1.0f / (float)E;
    float m = stats[lane] * invE;
    float v = stats[64 + lane] * invE - m * m;
    float scg = gg[lane] * rsqrtf(fmaxf(v, 0.f) + EPS);
    float shg = gb[lane] - m * scg;
    m = stats[128 + lane] * invE;
    v = stats[192 + lane] * invE - m * m;
    float scs = sg[lane] * rsqrtf(fmaxf(v, 0.f) + EPS);
    float shs = sb[lane] - m * scs;
    float cs = 0.f, cq = 0.f;
    int nw = gridDim.x * 4;
    for (int n = blockIdx.x * 4 + wid; n < N; n += nw) {
        int rp0 = rowptr[n], rp1 = rowptr[n + 1];
        float acc = 0.f;
        for (int i = rp0; i < rp1; i++) {
            int e = csr[i];
            unsigned pk = PREc[(size_t)e * 64 + lane];
            float yg = scg * lo2f(pk) + shg;
            float ys = scs * hi2f(pk) + shs;
            acc += softplusf(ys) / (1.f + expf(-yg));
        }
        upd[(size_t)n * D + lane] = acc;
        cs += acc; cq += acc * acc;
    }
    red[wid][0][lane] = cs; red[wid][1][lane] = cq;
    __syncthreads();
    if (tid < 64) {
        float a = red[0][0][lane] + red[1][0][lane] + red[2][0][lane] + red[3][0][lane];
        float b = red[0][1][lane] + red[1][1][lane] + red[2][1][lane] + red[3][1][lane];
        atomicAdd(&ustats[lane], a);
        atomicAdd(&ustats[64 + lane], b);
    }
}

// ---------------- h = softplus(BN(upd) + h)
__global__ void k_updapply(const float* __restrict__ upd, const float* __restrict__ stats,
                           const float* __restrict__ g, const float* __restrict__ beta,
                           float* __restrict__ h, int N, float invn) {
    int idx = blockIdx.x * blockDim.x + threadIdx.x;
    int total = N * D / 4;
    if (idx >= total) return;
    int c0 = (idx * 4) & 63;
    float4 u = ((const float4*)upd)[idx];
    float4 hh = ((const float4*)h)[idx];
    float uv[4] = {u.x, u.y, u.z, u.w}, hv[4] = {hh.x, hh.y, hh.z, hh.w}, o[4];
#pragma unroll
    for (int t = 0; t < 4; t++) {
        int c = c0 + t;
        float m = stats[c] * invn, v = stats[64 + c] * invn - m * m;
        float sc = g[c] * rsqrtf(fmaxf(v, 0.f) + EPS);
        float sh = beta[c] - m * sc;
        o[t] = softplusf(sc * uv[t] + sh + hv[t]);
    }
    ((float4*)h)[idx] = make_float4(o[0], o[1], o[2], o[3]);
}

// ---------------- segment-sum pool (batch sorted)
__global__ __launch_bounds__(256) void k_pool(const float* __restrict__ h, const int* __restrict__ batch,
                                              float* __restrict__ pool, float* __restrict__ cnt, int N) {
    int tid = threadIdx.x, lane = tid & 63, wid = tid >> 6;
    int w = blockIdx.x * 4 + wid, nw = gridDim.x * 4;
    int chunk = (N + nw - 1) / nw;
    int r0 = w * chunk, r1 = min(N, r0 + chunk);
    if (r0 >= r1) return;
    int cur = batch[r0];
    float acc = 0.f, c = 0.f;
    for (int r = r0; r < r1; r++) {
        int b = batch[r];
        if (b != cur) {
            atomicAdd(&pool[(size_t)cur * D + lane], acc);
            if (lane == 0) atomicAdd(&cnt[cur], c);
            acc = 0.f; c = 0.f; cur = b;
        }
        acc += h[(size_t)r * D + lane];
        c += 1.f;
    }
    atomicAdd(&pool[(size_t)cur * D + lane], acc);
    if (lane == 0) atomicAdd(&cnt[cur], c);
}

// ---------------- fc
__global__ __launch_bounds__(128) void k_fc(const float* __restrict__ pool, const float* __restrict__ cnt,
                                            const float* __restrict__ fcW, const float* __restrict__ fcb,
                                            float* __restrict__ Y, float* __restrict__ ystats) {
    int g = blockIdx.x;
    int j = threadIdx.x;
    __shared__ float vt[FCW];
    {
        float s, c;
        if (j < 64) { s = pool[(size_t)g * D + j]; c = cnt[g]; }
        else { s = pool[4096 + (size_t)g * D + (j - 64)]; c = cnt[64 + g]; }
        vt[j] = s / fmaxf(c, 1.0f);
    }
    __syncthreads();
    float acc = fcb[j];
#pragma unroll
    for (int k4 = 0; k4 < FCW; k4 += 4) {
        float4 v = *(const float4*)&vt[k4];
        acc += v.x * fcW[(k4 + 0) * FCW + j] + v.y * fcW[(k4 + 1) * FCW + j] +
               v.z * fcW[(k4 + 2) * FCW + j] + v.w * fcW[(k4 + 3) * FCW + j];
    }
    Y[(size_t)g * FCW + j] = acc;
    atomicAdd(&ystats[j], acc);
    atomicAdd(&ystats[128 + j], acc * acc);
}

// ---------------- head
__global__ __launch_bounds__(128) void k_head(const float* __restrict__ Y, const float* __restrict__ ystats,
                                              const float* __restrict__ fg, const float* __restrict__ fb,
                                              const float* __restrict__ pW, const float* __restrict__ pb,
                                              float* __restrict__ out) {
    int j = threadIdx.x;
    __shared__ float ys[NG][FCW + 1];
    __shared__ float pw[FCW];
    float invn = 1.0f / (float)NG;
    float m = ystats[j] * invn, v = ystats[128 + j] * invn - m * m;
    float sc = fg[j] * rsqrtf(fmaxf(v, 0.f) + EPS);
    float sh = fb[j] - m * sc;
    for (int g = 0; g < NG; g++) {
        float y = sc * Y[(size_t)g * FCW + j] + sh;
        ys[g][j] = y / (1.f + expf(-y));
    }
    pw[j] = pW[j];
    __syncthreads();
    if (j < NG) {
        float acc = pb[0];
        for (int k = 0; k < FCW; k++) acc += ys[j][k] * pw[k];
        out[j] = acc;
    }
}

// ---------------- workspace layout (bytes)
static const size_t OFF_EMBSTATS = 0;            // [2][128] f32
static const size_t OFF_EDGESTATS = 1024;        // [6][256] f32
static const size_t OFF_UPDSTATS = 7168;         // [6][128] f32
static const size_t OFF_POOL = 10240;            // [2][4096] f32
static const size_t OFF_CNT = 43008;             // [2][64] f32
static const size_t OFF_YSTATS = 43520;          // [256] f32
static const size_t OFF_DEG = 44544;             // [2][30000] int
static const size_t OFF_CURSOR = 284544;         // [2][30000] int
static const size_t MEMSET_BYTES = 524544;
static const size_t OFF_ROWPTR = 524544;         // [2][30016] int
static const size_t OFF_Y = 764672;              // [64][128] f32
static const size_t OFF_CSR = 797440;            // [2][360000] int
static const size_t OFF_H = 3677440;             // 30000*64 f32
static const size_t OFF_UPD = 11357440;          // 30000*64 f32 (also emb preact)
static const size_t OFF_SRCTAB = 19037440;       // 30000*64 u32 (bf16x2)
static const size_t OFF_DSTTAB = 26717440;
static const size_t OFF_PREC = 34397440;         // 360000*64 u32 (bf16x2)

extern "C" void kernel_launch(void* const* d_in, const int* in_sizes, int n_in,
                              void* d_out, int out_size, void* d_ws, size_t ws_size,
                              hipStream_t stream) {
    char* ws = (char*)d_ws;
    hipMemsetAsync(d_ws, 0, MEMSET_BYTES, stream);

    float* h = (float*)(ws + OFF_H);
    float* upd = (float*)(ws + OFF_UPD);
    unsigned* SRCT = (unsigned*)(ws + OFF_SRCTAB);
    unsigned* DSTT = (unsigned*)(ws + OFF_DSTTAB);
    unsigned* PREc = (unsigned*)(ws + OFF_PREC);

    for (int br = 0; br < 2; br++) {
        const float* vf = (const float*)d_in[br ? 2 : 0];
        const float* ef = (const float*)d_in[br ? 3 : 1];
        const int* srci = (const int*)d_in[br ? 7 : 4];
        const int* dsti = (const int*)d_in[br ? 8 : 5];
        const int* bat = (const int*)d_in[br ? 9 : 6];
        const float* embW = (const float*)d_in[br ? 14 : 10];
        const float* embB = (const float*)d_in[br ? 15 : 11];
        const float* embG = (const float*)d_in[br ? 16 : 12];
        const float* embBe = (const float*)d_in[br ? 17 : 13];
        const float* convW = (const float*)d_in[br ? 24 : 18];
        const float* convG = (const float*)d_in[br ? 26 : 20];
        const float* convBe = (const float*)d_in[br ? 27 : 21];
        const float* convNG = (const float*)d_in[br ? 28 : 22];
        const float* convNB = (const float*)d_in[br ? 29 : 23];

        float* embstats = (float*)(ws + OFF_EMBSTATS) + br * 128;
        float* poolp = (float*)(ws + OFF_POOL) + br * 4096;
        float* cntp = (float*)(ws + OFF_CNT) + br * 64;
        int* deg = (int*)(ws + OFF_DEG) + br * 30000;
        int* cursor = (int*)(ws + OFF_CURSOR) + br * 30000;
        int* rowptr = (int*)(ws + OFF_ROWPTR) + br * 30016;
        int* csr = (int*)(ws + OFF_CSR) + br * 360000;

        // CSR (dst) build — once per branch, reused across layers
        k_hist<<<512, 256, 0, stream>>>(dsti, deg, NEDGE);
        k_scan<<<1, 1024, 0, stream>>>(deg, rowptr, cursor, NNODE);
        k_fill<<<512, 256, 0, stream>>>(dsti, cursor, csr, NEDGE);

        k_emb_mm<<<(NNODE + EMB_RPB - 1) / EMB_RPB, 256, 0, stream>>>(vf, embW, embB, upd, embstats, NNODE);
        k_bnsilu<<<NNODE * D / 4 / 256, 256, 0, stream>>>(upd, embstats, embG, embBe, h, NNODE, 1.0f / NNODE);

        for (int i = 0; i < LAY; i++) {
            const float* Wc = convW + (size_t)i * 2 * 169 * 64;
            float* estats = (float*)(ws + OFF_EDGESTATS) + (br * 3 + i) * 256;
            float* ustats = (float*)(ws + OFF_UPDSTATS) + (br * 3 + i) * 128;
            const float* gg = convG + (i * 2 + 0) * 64;
            const float* gb = convBe + (i * 2 + 0) * 64;
            const float* sg = convG + (i * 2 + 1) * 64;
            const float* sb = convBe + (i * 2 + 1) * 64;

            k_nodeproj<<<(NNODE + NP_RPB - 1) / NP_RPB, 256, 0, stream>>>(h, Wc, SRCT, DSTT, NNODE);
            k_conv_gemm<<<NEDGE / 64, 256, 0, stream>>>(srci, dsti, ef, Wc, SRCT, DSTT, PREc, estats, upd, NEDGE, NNODE);
            k_conv_apply<<<1024, 256, 0, stream>>>(rowptr, csr, PREc, estats, gg, gb, sg, sb, upd, ustats, NEDGE, NNODE);
            k_updapply<<<NNODE * D / 4 / 256, 256, 0, stream>>>(upd, ustats, convNG + i * 64, convNB + i * 64, h, NNODE, 1.0f / NNODE);
        }
        k_pool<<<128, 256, 0, stream>>>(h, bat, poolp, cntp, NNODE);
    }

    float* poolall = (float*)(ws + OFF_POOL);
    float* cntall = (float*)(ws + OFF_CNT);
    float* Y = (float*)(ws + OFF_Y);
    float* ystats = (float*)(ws + OFF_YSTATS);
    k_fc<<<64, 128, 0, stream>>>(poolall, cntall, (const float*)d_in[30], (const float*)d_in[31], Y, ystats);
    k_head<<<1, 128, 0, stream>>>(Y, ystats, (const float*)d_in[32], (const float*)d_in[33],
                                  (const float*)d_in[34], (const float*)d_in[35], (float*)d_out);
}

// Round 6
// 2514.241 us; speedup vs baseline: 1.0128x; 1.0128x over previous
//
#include <hip/hip_runtime.h>
#include <cstddef>

#define EPS 1e-5f
#define NNODE 30000
#define NEDGE 360000
#define NFEAT 92
#define EF 41
#define D 64
#define LAY 3
#define FCW 128
#define NG 64

typedef unsigned short bf16;

__device__ __forceinline__ float b2f(bf16 u) { return __uint_as_float(((unsigned)u) << 16); }
__device__ __forceinline__ float lo2f(unsigned u) { return __uint_as_float(u << 16); }
__device__ __forceinline__ float hi2f(unsigned u) { return __uint_as_float(u & 0xffff0000u); }
__device__ __forceinline__ bf16 f2b(float f) {
    unsigned u = __float_as_uint(f);
    unsigned r = (u + 0x7FFFu + ((u >> 16) & 1u)) >> 16;
    return (bf16)r;
}
__device__ __forceinline__ float softplusf(float x) {
    return fmaxf(x, 0.0f) + log1pf(expf(-fabsf(x)));
}
__device__ __forceinline__ float edgeval(unsigned pk, float scg, float shg, float scs, float shs) {
    float yg = scg * lo2f(pk) + shg;
    float ys = scs * hi2f(pk) + shs;
    return softplusf(ys) / (1.f + expf(-yg));
}

// ---------------- embedding matmul: pre = X[N,92] @ W[92,64] + b, accumulate col stats
#define EMB_RPB 64
__global__ __launch_bounds__(256) void k_emb_mm(const float* __restrict__ X, const float* __restrict__ W,
                                                const float* __restrict__ bias, float* __restrict__ pre,
                                                float* __restrict__ stats, int N) {
    __shared__ float xs[EMB_RPB][NFEAT];
    __shared__ float red[4][2][64];
    int tid = threadIdx.x;
    int lane = tid & 63, wid = tid >> 6;
    int r0 = blockIdx.x * EMB_RPB;
    float w[NFEAT];
#pragma unroll
    for (int k = 0; k < NFEAT; k++) w[k] = W[k * D + lane];
    float bcol = bias[lane];
    for (int i = tid; i < EMB_RPB * (NFEAT / 4); i += 256) {
        int rr = i / (NFEAT / 4), kk = i - rr * (NFEAT / 4);
        int r = r0 + rr;
        float4 v = (r < N) ? ((const float4*)(X + (size_t)r * NFEAT))[kk] : make_float4(0, 0, 0, 0);
        *(float4*)&xs[rr][kk * 4] = v;
    }
    __syncthreads();
    float s0 = 0.f, s1 = 0.f;
    for (int rr = wid * 16; rr < wid * 16 + 16; rr++) {
        int r = r0 + rr;
        if (r >= N) break;
        float acc = bcol;
#pragma unroll
        for (int k4 = 0; k4 < NFEAT; k4 += 4) {
            float4 xv = *(const float4*)&xs[rr][k4];
            acc += xv.x * w[k4] + xv.y * w[k4 + 1] + xv.z * w[k4 + 2] + xv.w * w[k4 + 3];
        }
        pre[r * D + lane] = acc;
        s0 += acc; s1 += acc * acc;
    }
    red[wid][0][lane] = s0; red[wid][1][lane] = s1;
    __syncthreads();
    if (tid < 64) {
        float a = red[0][0][lane] + red[1][0][lane] + red[2][0][lane] + red[3][0][lane];
        float b = red[0][1][lane] + red[1][1][lane] + red[2][1][lane] + red[3][1][lane];
        atomicAdd(&stats[lane], a);
        atomicAdd(&stats[64 + lane], b);
    }
}

// ---------------- BN + SiLU elementwise
__global__ void k_bnsilu(const float* __restrict__ pre, const float* __restrict__ stats,
                         const float* __restrict__ g, const float* __restrict__ beta,
                         float* __restrict__ h, int N, float invn) {
    int idx = blockIdx.x * blockDim.x + threadIdx.x;
    int total = N * D / 4;
    if (idx >= total) return;
    int c0 = (idx * 4) & 63;
    float4 p = ((const float4*)pre)[idx];
    float pv[4] = {p.x, p.y, p.z, p.w}, o[4];
#pragma unroll
    for (int t = 0; t < 4; t++) {
        int c = c0 + t;
        float m = stats[c] * invn;
        float v = stats[64 + c] * invn - m * m;
        float sc = g[c] * rsqrtf(fmaxf(v, 0.f) + EPS);
        float sh = beta[c] - m * sc;
        float y = sc * pv[t] + sh;
        o[t] = y / (1.f + expf(-y));
    }
    ((float4*)h)[idx] = make_float4(o[0], o[1], o[2], o[3]);
}

// ---------------- CSR build: histogram, block scan, fill (perm only)
__global__ __launch_bounds__(256) void k_hist(const int* __restrict__ dst, int* __restrict__ deg, int E) {
    int i = blockIdx.x * 256 + threadIdx.x, gs = gridDim.x * 256;
    for (; i < E; i += gs) atomicAdd(&deg[dst[i]], 1);
}
__global__ __launch_bounds__(1024) void k_scan(const int* __restrict__ deg, int* __restrict__ rowptr,
                                               int* __restrict__ cursor, int N) {
    __shared__ int part[1024];
    int t = threadIdx.x;
    int chunk = (N + 1023) / 1024;
    int c0 = t * chunk, c1 = min(N, c0 + chunk);
    int s = 0;
    for (int i = c0; i < c1; i++) s += deg[i];
    part[t] = s;
    __syncthreads();
    for (int off = 1; off < 1024; off <<= 1) {
        int v = (t >= off) ? part[t - off] : 0;
        __syncthreads();
        part[t] += v;
        __syncthreads();
    }
    int base = (t == 0) ? 0 : part[t - 1];
    int r = base;
    for (int i = c0; i < c1; i++) {
        rowptr[i] = r; cursor[i] = r; r += deg[i];
    }
    if (t == 1023) rowptr[N] = part[1023];
}
__global__ __launch_bounds__(256) void k_fill(const int* __restrict__ dst, int* __restrict__ cursor,
                                              int* __restrict__ perm, int E) {
    int i = blockIdx.x * 256 + threadIdx.x, gs = gridDim.x * 256;
    for (; i < E; i += gs) {
        int p = atomicAdd(&cursor[dst[i]], 1);
        perm[i] = p;
    }
}

// ---------------- node projections -> ushort2 tables: SRCT[n*64+j]={gate,scr}, DSTT likewise
#define NP_RPB 32
__global__ __launch_bounds__(256) void k_nodeproj(const float* __restrict__ h, const float* __restrict__ Wc,
                                                  unsigned* __restrict__ SRC, unsigned* __restrict__ DST, int N) {
    __shared__ float hs[NP_RPB][D];   // 8 KB
    int tid = threadIdx.x;
    int j = tid & 63;
    int wid = __builtin_amdgcn_readfirstlane(tid >> 6);
    int pairIdx = wid & 1;            // 0: SRC (comb rows 0..63), 1: DST (rows 64..127)
    int half = wid >> 1;
    int roff = pairIdx * 64;
    float wg[D], wsx[D];
#pragma unroll
    for (int k = 0; k < D; k++) {
        wg[k] = Wc[(size_t)(roff + k) * 64 + j];
        wsx[k] = Wc[(size_t)(169 + roff + k) * 64 + j];
    }
    int r0 = blockIdx.x * NP_RPB;
    for (int i = tid; i < NP_RPB * D / 4; i += 256) {
        int rr = i >> 4, kk = (i & 15);
        int r = r0 + rr;
        float4 v = (r < N) ? ((const float4*)(h + (size_t)r * D))[kk] : make_float4(0, 0, 0, 0);
        *(float4*)&hs[rr][kk * 4] = v;
    }
    __syncthreads();
    unsigned* out = pairIdx ? DST : SRC;
    int rlo = half * 16, rhi = min(half * 16 + 16, N - r0);
    for (int rr = rlo; rr < rhi; rr++) {
        float ag = 0.f, as = 0.f;
#pragma unroll
        for (int k4 = 0; k4 < D; k4 += 4) {
            float4 xv = *(const float4*)&hs[rr][k4];
            ag += xv.x * wg[k4] + xv.y * wg[k4 + 1] + xv.z * wg[k4 + 2] + xv.w * wg[k4 + 3];
            as += xv.x * wsx[k4] + xv.y * wsx[k4 + 1] + xv.z * wsx[k4 + 2] + xv.w * wsx[k4 + 3];
        }
        unsigned pk = (unsigned)f2b(ag) | ((unsigned)f2b(as) << 16);
        out[(size_t)(r0 + rr) * 64 + j] = pk;
    }
}

// ---------------- conv GEMM: 64-edge tile, 4-edge groups (gather prefetch);
// stores PREc in CSR order via perm; stats on f32; fused upd zeroing.
__global__ __launch_bounds__(256) void k_conv_gemm(const int* __restrict__ src, const int* __restrict__ dst,
                                                   const int* __restrict__ perm,
                                                   const float* __restrict__ ef, const float* __restrict__ Wc,
                                                   const unsigned* __restrict__ SRCT, const unsigned* __restrict__ DSTT,
                                                   unsigned* __restrict__ PREc, float* __restrict__ stats,
                                                   float* __restrict__ upd, int E, int N) {
    __shared__ float els[64][44];      // 11.3 KB
    __shared__ float red[4][4][64];
    int tid = threadIdx.x, lane = tid & 63;
    int wid = __builtin_amdgcn_readfirstlane(tid >> 6);
    {   // fused zeroing of upd
        int gsz = gridDim.x * 256;
        for (int i = blockIdx.x * 256 + tid; i < N * D; i += gsz) upd[i] = 0.f;
    }
    float wg[EF], wsc[EF];
#pragma unroll
    for (int k = 0; k < EF; k++) {
        wg[k] = Wc[(size_t)(128 + k) * 64 + lane];
        wsc[k] = Wc[(size_t)(169 + 128 + k) * 64 + lane];
    }
    int e0 = blockIdx.x * 64;
    const float* gbase = ef + (size_t)e0 * EF;
    for (int i = tid; i < 64 * EF; i += 256) {
        int rr = i / EF, kk = i - rr * EF;
        els[rr][kk] = gbase[i];
    }
    __syncthreads();
    float a0 = 0, a1 = 0, a2 = 0, a3 = 0;
#pragma unroll 1
    for (int g4 = 0; g4 < 4; g4++) {
        int le0 = wid * 16 + g4 * 4;
        int sA[4], dA[4], pm[4];
#pragma unroll
        for (int t = 0; t < 4; t++) {
            int e = e0 + le0 + t;
            sA[t] = src[e]; dA[t] = dst[e]; pm[t] = perm[e];
        }
        unsigned us[4], ud[4];
#pragma unroll
        for (int t = 0; t < 4; t++) {
            us[t] = SRCT[(size_t)sA[t] * 64 + lane];
            ud[t] = DSTT[(size_t)dA[t] * 64 + lane];
        }
#pragma unroll
        for (int t = 0; t < 4; t++) {
            int le = le0 + t;
            float pg = lo2f(us[t]) + lo2f(ud[t]);
            float ps = hi2f(us[t]) + hi2f(ud[t]);
            float qg = 0.f, qs = 0.f;
#pragma unroll
            for (int k4 = 0; k4 < 40; k4 += 4) {
                float4 ev = *(const float4*)&els[le][k4];
                if (((k4 >> 2) & 1) == 0) {
                    pg += ev.x * wg[k4] + ev.y * wg[k4 + 1] + ev.z * wg[k4 + 2] + ev.w * wg[k4 + 3];
                    ps += ev.x * wsc[k4] + ev.y * wsc[k4 + 1] + ev.z * wsc[k4 + 2] + ev.w * wsc[k4 + 3];
                } else {
                    qg += ev.x * wg[k4] + ev.y * wg[k4 + 1] + ev.z * wg[k4 + 2] + ev.w * wg[k4 + 3];
                    qs += ev.x * wsc[k4] + ev.y * wsc[k4 + 1] + ev.z * wsc[k4 + 2] + ev.w * wsc[k4 + 3];
                }
            }
            {
                float ev = els[le][40];
                qg += ev * wg[40]; qs += ev * wsc[40];
            }
            pg += qg; ps += qs;
            a0 += pg; a1 += pg * pg; a2 += ps; a3 += ps * ps;
            unsigned pk = (unsigned)f2b(pg) | ((unsigned)f2b(ps) << 16);
            PREc[(size_t)pm[t] * 64 + lane] = pk;
        }
    }
    red[wid][0][lane] = a0; red[wid][1][lane] = a1; red[wid][2][lane] = a2; red[wid][3][lane] = a3;
    __syncthreads();
    if (tid < 64) {
#pragma unroll
        for (int t = 0; t < 4; t++) {
            float v = red[0][t][lane] + red[1][t][lane] + red[2][t][lane] + red[3][t][lane];
            atomicAdd(&stats[t * 64 + lane], v);
        }
    }
}

// ---------------- conv apply: PREc is in CSR order -> fully streaming reads,
// contiguous node ranges per wave, no atomics on upd, fused colstats
__global__ __launch_bounds__(256) void k_conv_apply(const int* __restrict__ rowptr,
                                                    const unsigned* __restrict__ PREc, const float* __restrict__ stats,
                                                    const float* __restrict__ gg, const float* __restrict__ gb,
                                                    const float* __restrict__ sg, const float* __restrict__ sb,
                                                    float* __restrict__ upd, float* __restrict__ ustats,
                                                    int E, int N) {
    __shared__ float red[4][2][64];
    int tid = threadIdx.x, lane = tid & 63;
    int wid = __builtin_amdgcn_readfirstlane(tid >> 6);
    float invE = 1.0f / (float)E;
    float m = stats[lane] * invE;
    float v = stats[64 + lane] * invE - m * m;
    float scg = gg[lane] * rsqrtf(fmaxf(v, 0.f) + EPS);
    float shg = gb[lane] - m * scg;
    m = stats[128 + lane] * invE;
    v = stats[192 + lane] * invE - m * m;
    float scs = sg[lane] * rsqrtf(fmaxf(v, 0.f) + EPS);
    float shs = sb[lane] - m * scs;
    float cs = 0.f, cq = 0.f;
    int w = blockIdx.x * 4 + wid, nw = gridDim.x * 4;
    int chunk = (N + nw - 1) / nw;
    int n0 = w * chunk, n1 = min(N, n0 + chunk);
    for (int n = n0; n < n1; n++) {
        int rp0 = rowptr[n], rp1 = rowptr[n + 1];
        float acc = 0.f;
        int i = rp0;
        for (; i + 4 <= rp1; i += 4) {
            unsigned p0 = PREc[(size_t)(i + 0) * 64 + lane];
            unsigned p1 = PREc[(size_t)(i + 1) * 64 + lane];
            unsigned p2 = PREc[(size_t)(i + 2) * 64 + lane];
            unsigned p3 = PREc[(size_t)(i + 3) * 64 + lane];
            acc += edgeval(p0, scg, shg, scs, shs) + edgeval(p1, scg, shg, scs, shs) +
                   edgeval(p2, scg, shg, scs, shs) + edgeval(p3, scg, shg, scs, shs);
        }
        for (; i < rp1; i++) acc += edgeval(PREc[(size_t)i * 64 + lane], scg, shg, scs, shs);
        upd[(size_t)n * D + lane] = acc;
        cs += acc; cq += acc * acc;
    }
    red[wid][0][lane] = cs; red[wid][1][lane] = cq;
    __syncthreads();
    if (tid < 64) {
        float a = red[0][0][lane] + red[1][0][lane] + red[2][0][lane] + red[3][0][lane];
        float b = red[0][1][lane] + red[1][1][lane] + red[2][1][lane] + red[3][1][lane];
        atomicAdd(&ustats[lane], a);
        atomicAdd(&ustats[64 + lane], b);
    }
}

// ---------------- h = softplus(BN(upd) + h)
__global__ void k_updapply(const float* __restrict__ upd, const float* __restrict__ stats,
                           const float* __restrict__ g, const float* __restrict__ beta,
                           float* __restrict__ h, int N, float invn) {
    int idx = blockIdx.x * blockDim.x + threadIdx.x;
    int total = N * D / 4;
    if (idx >= total) return;
    int c0 = (idx * 4) & 63;
    float4 u = ((const float4*)upd)[idx];
    float4 hh = ((const float4*)h)[idx];
    float uv[4] = {u.x, u.y, u.z, u.w}, hv[4] = {hh.x, hh.y, hh.z, hh.w}, o[4];
#pragma unroll
    for (int t = 0; t < 4; t++) {
        int c = c0 + t;
        float m = stats[c] * invn, v = stats[64 + c] * invn - m * m;
        float sc = g[c] * rsqrtf(fmaxf(v, 0.f) + EPS);
        float sh = beta[c] - m * sc;
        o[t] = softplusf(sc * uv[t] + sh + hv[t]);
    }
    ((float4*)h)[idx] = make_float4(o[0], o[1], o[2], o[3]);
}

// ---------------- segment-sum pool (batch sorted)
__global__ __launch_bounds__(256) void k_pool(const float* __restrict__ h, const int* __restrict__ batch,
                                              float* __restrict__ pool, float* __restrict__ cnt, int N) {
    int tid = threadIdx.x, lane = tid & 63, wid = tid >> 6;
    int w = blockIdx.x * 4 + wid, nw = gridDim.x * 4;
    int chunk = (N + nw - 1) / nw;
    int r0 = w * chunk, r1 = min(N, r0 + chunk);
    if (r0 >= r1) return;
    int cur = batch[r0];
    float acc = 0.f, c = 0.f;
    for (int r = r0; r < r1; r++) {
        int b = batch[r];
        if (b != cur) {
            atomicAdd(&pool[(size_t)cur * D + lane], acc);
            if (lane == 0) atomicAdd(&cnt[cur], c);
            acc = 0.f; c = 0.f; cur = b;
        }
        acc += h[(size_t)r * D + lane];
        c += 1.f;
    }
    atomicAdd(&pool[(size_t)cur * D + lane], acc);
    if (lane == 0) atomicAdd(&cnt[cur], c);
}

// ---------------- fc
__global__ __launch_bounds__(128) void k_fc(const float* __restrict__ pool, const float* __restrict__ cnt,
                                            const float* __restrict__ fcW, const float* __restrict__ fcb,
                                            float* __restrict__ Y, float* __restrict__ ystats) {
    int g = blockIdx.x;
    int j = threadIdx.x;
    __shared__ float vt[FCW];
    {
        float s, c;
        if (j < 64) { s = pool[(size_t)g * D + j]; c = cnt[g]; }
        else { s = pool[4096 + (size_t)g * D + (j - 64)]; c = cnt[64 + g]; }
        vt[j] = s / fmaxf(c, 1.0f);
    }
    __syncthreads();
    float acc = fcb[j];
#pragma unroll
    for (int k4 = 0; k4 < FCW; k4 += 4) {
        float4 v = *(const float4*)&vt[k4];
        acc += v.x * fcW[(k4 + 0) * FCW + j] + v.y * fcW[(k4 + 1) * FCW + j] +
               v.z * fcW[(k4 + 2) * FCW + j] + v.w * fcW[(k4 + 3) * FCW + j];
    }
    Y[(size_t)g * FCW + j] = acc;
    atomicAdd(&ystats[j], acc);
    atomicAdd(&ystats[128 + j], acc * acc);
}

// ---------------- head
__global__ __launch_bounds__(128) void k_head(const float* __restrict__ Y, const float* __restrict__ ystats,
                                              const float* __restrict__ fg, const float* __restrict__ fb,
                                              const float* __restrict__ pW, const float* __restrict__ pb,
                                              float* __restrict__ out) {
    int j = threadIdx.x;
    __shared__ float ys[NG][FCW + 1];
    __shared__ float pw[FCW];
    float invn = 1.0f / (float)NG;
    float m = ystats[j] * invn, v = ystats[128 + j] * invn - m * m;
    float sc = fg[j] * rsqrtf(fmaxf(v, 0.f) + EPS);
    float sh = fb[j] - m * sc;
    for (int g = 0; g < NG; g++) {
        float y = sc * Y[(size_t)g * FCW + j] + sh;
        ys[g][j] = y / (1.f + expf(-y));
    }
    pw[j] = pW[j];
    __syncthreads();
    if (j < NG) {
        float acc = pb[0];
        for (int k = 0; k < FCW; k++) acc += ys[j][k] * pw[k];
        out[j] = acc;
    }
}

// ---------------- workspace layout (bytes)
static const size_t OFF_EMBSTATS = 0;            // [2][128] f32
static const size_t OFF_EDGESTATS = 1024;        // [6][256] f32
static const size_t OFF_UPDSTATS = 7168;         // [6][128] f32
static const size_t OFF_POOL = 10240;            // [2][4096] f32
static const size_t OFF_CNT = 43008;             // [2][64] f32
static const size_t OFF_YSTATS = 43520;          // [256] f32
static const size_t OFF_DEG = 44544;             // [2][30000] int
static const size_t OFF_CURSOR = 284544;         // [2][30000] int
static const size_t MEMSET_BYTES = 524544;
static const size_t OFF_ROWPTR = 524544;         // [2][30016] int
static const size_t OFF_Y = 764672;              // [64][128] f32
static const size_t OFF_PERM = 797440;           // [2][360000] int
static const size_t OFF_H = 3677440;             // 30000*64 f32
static const size_t OFF_UPD = 11357440;          // 30000*64 f32 (also emb preact)
static const size_t OFF_SRCTAB = 19037440;       // 30000*64 u32 (bf16x2)
static const size_t OFF_DSTTAB = 26717440;
static const size_t OFF_PREC = 34397440;         // 360000*64 u32 (bf16x2), CSR-ordered

extern "C" void kernel_launch(void* const* d_in, const int* in_sizes, int n_in,
                              void* d_out, int out_size, void* d_ws, size_t ws_size,
                              hipStream_t stream) {
    char* ws = (char*)d_ws;
    hipMemsetAsync(d_ws, 0, MEMSET_BYTES, stream);

    float* h = (float*)(ws + OFF_H);
    float* upd = (float*)(ws + OFF_UPD);
    unsigned* SRCT = (unsigned*)(ws + OFF_SRCTAB);
    unsigned* DSTT = (unsigned*)(ws + OFF_DSTTAB);
    unsigned* PREc = (unsigned*)(ws + OFF_PREC);

    for (int br = 0; br < 2; br++) {
        const float* vf = (const float*)d_in[br ? 2 : 0];
        const float* ef = (const float*)d_in[br ? 3 : 1];
        const int* srci = (const int*)d_in[br ? 7 : 4];
        const int* dsti = (const int*)d_in[br ? 8 : 5];
        const int* bat = (const int*)d_in[br ? 9 : 6];
        const float* embW = (const float*)d_in[br ? 14 : 10];
        const float* embB = (const float*)d_in[br ? 15 : 11];
        const float* embG = (const float*)d_in[br ? 16 : 12];
        const float* embBe = (const float*)d_in[br ? 17 : 13];
        const float* convW = (const float*)d_in[br ? 24 : 18];
        const float* convG = (const float*)d_in[br ? 26 : 20];
        const float* convBe = (const float*)d_in[br ? 27 : 21];
        const float* convNG = (const float*)d_in[br ? 28 : 22];
        const float* convNB = (const float*)d_in[br ? 29 : 23];

        float* embstats = (float*)(ws + OFF_EMBSTATS) + br * 128;
        float* poolp = (float*)(ws + OFF_POOL) + br * 4096;
        float* cntp = (float*)(ws + OFF_CNT) + br * 64;
        int* deg = (int*)(ws + OFF_DEG) + br * 30000;
        int* cursor = (int*)(ws + OFF_CURSOR) + br * 30000;
        int* rowptr = (int*)(ws + OFF_ROWPTR) + br * 30016;
        int* perm = (int*)(ws + OFF_PERM) + br * 360000;

        // CSR (dst) build — once per branch, reused across layers
        k_hist<<<512, 256, 0, stream>>>(dsti, deg, NEDGE);
        k_scan<<<1, 1024, 0, stream>>>(deg, rowptr, cursor, NNODE);
        k_fill<<<512, 256, 0, stream>>>(dsti, cursor, perm, NEDGE);

        k_emb_mm<<<(NNODE + EMB_RPB - 1) / EMB_RPB, 256, 0, stream>>>(vf, embW, embB, upd, embstats, NNODE);
        k_bnsilu<<<NNODE * D / 4 / 256, 256, 0, stream>>>(upd, embstats, embG, embBe, h, NNODE, 1.0f / NNODE);

        for (int i = 0; i < LAY; i++) {
            const float* Wc = convW + (size_t)i * 2 * 169 * 64;
            float* estats = (float*)(ws + OFF_EDGESTATS) + (br * 3 + i) * 256;
            float* ustats = (float*)(ws + OFF_UPDSTATS) + (br * 3 + i) * 128;
            const float* gg = convG + (i * 2 + 0) * 64;
            const float* gb = convBe + (i * 2 + 0) * 64;
            const float* sg = convG + (i * 2 + 1) * 64;
            const float* sb = convBe + (i * 2 + 1) * 64;

            k_nodeproj<<<(NNODE + NP_RPB - 1) / NP_RPB, 256, 0, stream>>>(h, Wc, SRCT, DSTT, NNODE);
            k_conv_gemm<<<NEDGE / 64, 256, 0, stream>>>(srci, dsti, perm, ef, Wc, SRCT, DSTT, PREc, estats, upd, NEDGE, NNODE);
            k_conv_apply<<<512, 256, 0, stream>>>(rowptr, PREc, estats, gg, gb, sg, sb, upd, ustats, NEDGE, NNODE);
            k_updapply<<<NNODE * D / 4 / 256, 256, 0, stream>>>(upd, ustats, convNG + i * 64, convNB + i * 64, h, NNODE, 1.0f / NNODE);
        }
        k_pool<<<128, 256, 0, stream>>>(h, bat, poolp, cntp, NNODE);
    }

    float* poolall = (float*)(ws + OFF_POOL);
    float* cntall = (float*)(ws + OFF_CNT);
    float* Y = (float*)(ws + OFF_Y);
    float* ystats = (float*)(ws + OFF_YSTATS);
    k_fc<<<64, 128, 0, stream>>>(poolall, cntall, (const float*)d_in[30], (const float*)d_in[31], Y, ystats);
    k_head<<<1, 128, 0, stream>>>(Y, ystats, (const float*)d_in[32], (const float*)d_in[33],
                                  (const float*)d_in[34], (const float*)d_in[35], (float*)d_out);
}